// Round 8
// baseline (263.128 us; speedup 1.0000x reference)
//
#include <hip/hip_runtime.h>

// x: (64, 8192, 256) float32, cumsum along dim 1.
#define BATCH 64
#define LEN   8192
#define DIM   256
#define D4    (DIM / 4)      // 64 float4 per row
#define Q     16             // chains per batch row-slice: 64 B per slice
#define SF4   (D4 / Q)       // 4 float4 per slice
#define R     8              // rows per thread per tile
#define GPW   16             // row-groups per wave (64 lanes / 4 f4)
#define TILE  (GPW * R)      // 128 rows per tile
#define NT    (LEN / TILE)   // 64 tiles, serial per wave (carry in regs)

typedef float vf4 __attribute__((ext_vector_type(4)));

__device__ __forceinline__ void f4_add(float4& a, const float4& v) {
    a.x += v.x; a.y += v.y; a.z += v.z; a.w += v.w;
}

// One WAVE owns the full 8192-row chain of a (batch, 16-channel slice).
// No LDS data path, no cross-wave dependency: intra-wave shfl scan only.
// Block = 2 waves = the q-pair sharing each 128 B line (same CU -> L1/L2
// absorbs the line sharing). One __syncthreads per tile paces the pair.
__global__ __launch_bounds__(128) void wave_scan_kernel(
    const float* __restrict__ x, float* __restrict__ out)
{
    const int bid  = blockIdx.x;        // 0..511
    const int b    = bid >> 3;          // batch
    const int qq   = bid & 7;           // 128 B line-pair slice
    const int w    = threadIdx.x >> 6;  // wave in block: 0..1
    const int lane = threadIdx.x & 63;
    const int q    = qq * 2 + w;        // 64 B slice owned by this wave
    const int f    = lane & (SF4 - 1);  // f4 within slice (0..3)
    const int g    = lane >> 2;         // row-group (0..15), R rows each

    const size_t chain = (size_t)b * LEN * D4 + (size_t)q * SF4 + f;
    const float4* xp = reinterpret_cast<const float4*>(x) + chain;
    float4*       op = reinterpret_cast<float4*>(out) + chain;
    const size_t r0 = (size_t)(g * R) * D4;   // thread's first row in a tile

    float4 carry = make_float4(0.f, 0.f, 0.f, 0.f);

    // Prefetch tile 0.
    float4 a[R];
#pragma unroll
    for (int r = 0; r < R; ++r) a[r] = xp[r0 + (size_t)r * D4];

    for (int tile = 0; tile < NT; ++tile) {
        // Issue next tile's loads first; 1-tile slack >> HBM latency.
        const int nxt = (tile + 1 < NT) ? tile + 1 : tile;
        const size_t nb = (size_t)nxt * TILE * D4 + r0;
        float4 nx[R];
#pragma unroll
        for (int r = 0; r < R; ++r) nx[r] = xp[nb + (size_t)r * D4];

        // 8-row group sum.
        float4 ls = a[0];
#pragma unroll
        for (int r = 1; r < R; ++r) f4_add(ls, a[r]);

        // Intra-wave inclusive scan over the 16 groups (stride-4 lanes).
        float4 incl = ls;
#pragma unroll
        for (int d = 1; d < GPW; d <<= 1) {
            float4 o;
            o.x = __shfl_up(incl.x, d * SF4, 64);
            o.y = __shfl_up(incl.y, d * SF4, 64);
            o.z = __shfl_up(incl.z, d * SF4, 64);
            o.w = __shfl_up(incl.w, d * SF4, 64);
            if (g >= d) f4_add(incl, o);
        }

        // Wave total = inclusive of last group (lanes 60..63, matching f).
        float4 tot;
        tot.x = __shfl(incl.x, 60 + f, 64);
        tot.y = __shfl(incl.y, 60 + f, 64);
        tot.z = __shfl(incl.z, 60 + f, 64);
        tot.w = __shfl(incl.w, 60 + f, 64);

        // acc = carry + exclusive-prefix-of-this-group = carry + incl - ls
        float4 acc = carry;
        f4_add(acc, incl);
        acc.x -= ls.x; acc.y -= ls.y; acc.z -= ls.z; acc.w -= ls.w;

        // Emit 8 output rows (nontemporal: out never re-read).
        const size_t ob = (size_t)tile * TILE * D4 + r0;
#pragma unroll
        for (int r = 0; r < R; ++r) {
            f4_add(acc, a[r]);
            __builtin_nontemporal_store(*reinterpret_cast<const vf4*>(&acc),
                                        reinterpret_cast<vf4*>(op + ob + (size_t)r * D4));
        }

        f4_add(carry, tot);
#pragma unroll
        for (int r = 0; r < R; ++r) a[r] = nx[r];

        // Cheap 2-wave pacing: keeps the q-pair temporally close so the
        // shared 128 B lines are served by L1/L2, not refetched from HBM.
        __syncthreads();
    }
}

extern "C" void kernel_launch(void* const* d_in, const int* in_sizes, int n_in,
                              void* d_out, int out_size, void* d_ws, size_t ws_size,
                              hipStream_t stream) {
    const float* x = (const float*)d_in[0];
    float* out = (float*)d_out;
    wave_scan_kernel<<<BATCH * 8, 128, 0, stream>>>(x, out);
}

// Round 9
// 225.391 us; speedup vs baseline: 1.1674x; 1.1674x over previous
//
#include <hip/hip_runtime.h>

// x: (64, 8192, 256) float32, cumsum along dim 1.
#define BATCH 64
#define LEN   8192
#define DIM   256
#define D4    (DIM / 4)        // 64 float4 per row
#define Q     8                // channel slices per batch (128 B/row slice = 1 cache line)
#define SF4   (D4 / Q)         // 8 float4 per slice
#define NTHR  512
#define R     4                // rows per thread per tile
#define GROUPS (NTHR / SF4)    // 64 row-groups per tile
#define TILE  (GROUPS * R)     // 256 rows per tile
#define NT    (LEN / TILE)     // 32 tiles, serial per block (carry in regs)
#define NWAVES (NTHR / 64)     // 8

__device__ __forceinline__ void f4_add(float4& a, const float4& v) {
    a.x += v.x; a.y += v.y; a.z += v.z; a.w += v.w;
}

// One block owns the full 8192-row chain of a (batch, 32-channel slice).
// Serial over 32 tiles of 256 rows; carry in registers; x read once, out once.
// KEY (round 9): stores of tile t are DEFERRED to iteration t+1 and issued
// right after t+1's prefetch loads, before the barrier — loads and stores
// stay simultaneously in flight (copy-like), instead of store bursts being
// pinned behind the barrier drain.
__global__ __launch_bounds__(NTHR, 2) void chained_scan_kernel(
    const float* __restrict__ x, float* __restrict__ out)
{
    __shared__ float4 wtot[2][NWAVES][SF4];   // 2 KiB

    const int q    = blockIdx.x;         // channel slice
    const int b    = blockIdx.y;         // batch
    const int t    = threadIdx.x;        // 0..511
    const int f    = t & (SF4 - 1);      // f4 within slice (0..7)
    const int g    = t >> 3;             // group within tile (0..63), 4 rows each
    const int lane = t & 63;
    const int w    = t >> 6;             // wave 0..7
    const int lg   = lane >> 3;          // local group within wave (0..7)

    const size_t chain = (size_t)b * LEN * D4 + (size_t)q * SF4 + f;
    const float4* xp = reinterpret_cast<const float4*>(x) + chain;
    float4*       op = reinterpret_cast<float4*>(out) + chain;
    const size_t r0 = (size_t)(g * R) * D4;  // thread's first row offset in a tile

    float4 carry = make_float4(0.f, 0.f, 0.f, 0.f);

    // Prefetch tile 0.
    float4 a[R];
#pragma unroll
    for (int r = 0; r < R; ++r) a[r] = xp[r0 + (size_t)r * D4];

    float4 held[R];                      // deferred output rows of previous tile
    size_t held_ob = 0;

    for (int tile = 0; tile < NT; ++tile) {
        // 1) Issue next tile's loads.
        const int nxt = (tile + 1 < NT) ? tile + 1 : tile;
        const size_t nb = (size_t)nxt * TILE * D4 + r0;
        float4 nx[R];
#pragma unroll
        for (int r = 0; r < R; ++r) nx[r] = xp[nb + (size_t)r * D4];

        // 2) Flush previous tile's outputs NOW — overlaps with the loads
        //    above and decouples stores from this tile's barrier.
        if (tile > 0) {
#pragma unroll
            for (int r = 0; r < R; ++r)
                op[held_ob + (size_t)r * D4] = held[r];
        }

        // 3) Tile scan. 4-row group sum:
        float4 ls = a[0];
        f4_add(ls, a[1]); f4_add(ls, a[2]); f4_add(ls, a[3]);

        // Wave-inclusive scan over the 8 local groups (same-f lanes, stride 8).
        float4 incl = ls;
#pragma unroll
        for (int d = 1; d < 8; d <<= 1) {
            float4 o;
            o.x = __shfl_up(incl.x, d * SF4, 64);
            o.y = __shfl_up(incl.y, d * SF4, 64);
            o.z = __shfl_up(incl.z, d * SF4, 64);
            o.w = __shfl_up(incl.w, d * SF4, 64);
            if (lg >= d) f4_add(incl, o);
        }

        // Publish per-wave totals (last local group holds them), parity-buffered.
        const int par = tile & 1;
        if (lane >= 56) wtot[par][w][f] = incl;
        __syncthreads();

        // Cross-wave exclusive prefix + tile total (8 broadcast reads).
        float4 cross = make_float4(0.f, 0.f, 0.f, 0.f);
        float4 tot   = make_float4(0.f, 0.f, 0.f, 0.f);
#pragma unroll
        for (int ww = 0; ww < NWAVES; ++ww) {
            float4 s = wtot[par][ww][f];
            if (ww < w) f4_add(cross, s);
            f4_add(tot, s);
        }

        // acc = carry + exclusive-prefix-of-this-group = carry + cross + incl - ls
        float4 acc = carry;
        f4_add(acc, cross);
        f4_add(acc, incl);
        acc.x -= ls.x; acc.y -= ls.y; acc.z -= ls.z; acc.w -= ls.w;

        // 4) Produce this tile's outputs into held registers (store next iter).
#pragma unroll
        for (int r = 0; r < R; ++r) {
            f4_add(acc, a[r]);
            held[r] = acc;
        }
        held_ob = (size_t)tile * TILE * D4 + r0;

        f4_add(carry, tot);
#pragma unroll
        for (int r = 0; r < R; ++r) a[r] = nx[r];
    }

    // Flush the final tile's outputs.
#pragma unroll
    for (int r = 0; r < R; ++r)
        op[held_ob + (size_t)r * D4] = held[r];
}

extern "C" void kernel_launch(void* const* d_in, const int* in_sizes, int n_in,
                              void* d_out, int out_size, void* d_ws, size_t ws_size,
                              hipStream_t stream) {
    const float* x = (const float*)d_in[0];
    float* out = (float*)d_out;
    chained_scan_kernel<<<dim3(Q, BATCH), NTHR, 0, stream>>>(x, out);
}